// Round 1
// baseline (3932.056 us; speedup 1.0000x reference)
//
#include <hip/hip_runtime.h>

#define NN 50000
#define NE 800000
#define DD 64
#define NL 5
#define NG 256
#define NC 10
#define BN_EPS 1e-5f

// ---------------------------------------------------------------------------
// Fused 4-matrix GEMM: K = Hin@Wk + bk, Q = Hin@Wq + bq, V = Hin@Wv + bv,
// OUT = Hin@Ws + bs  (OUT doubles as the conv accumulator; edge kernel adds).
// Block: 256 threads, 32-row tile. Weights (4 x 64x64) staged in LDS.
// ---------------------------------------------------------------------------
__global__ __launch_bounds__(256) void gemm4_kernel(
    const float* __restrict__ Hin,
    const float* __restrict__ Wk, const float* __restrict__ Wq,
    const float* __restrict__ Wv, const float* __restrict__ Ws,
    const float* __restrict__ bk, const float* __restrict__ bq,
    const float* __restrict__ bv, const float* __restrict__ bs,
    float* __restrict__ K, float* __restrict__ Q,
    float* __restrict__ V, float* __restrict__ OUT)
{
    __shared__ float sW[4][64 * 64];
    __shared__ float sX[32 * 64];
    const int tid = threadIdx.x;

    for (int i = tid; i < 4096; i += 256) {
        sW[0][i] = Wk[i];
        sW[1][i] = Wq[i];
        sW[2][i] = Wv[i];
        sW[3][i] = Ws[i];
    }

    const int row0 = blockIdx.x * 32;
    float4* sX4 = (float4*)sX;
    const float4* Hin4 = (const float4*)(Hin + (size_t)row0 * DD);
    for (int i = tid; i < 32 * 16; i += 256) {  // 512 float4 = 32x64 floats
        int r = row0 + (i >> 4);
        sX4[i] = (r < NN) ? Hin4[i] : make_float4(0.f, 0.f, 0.f, 0.f);
    }
    __syncthreads();

    const int c  = tid & 63;   // output column (lane)
    const int rg = tid >> 6;   // row group 0..3, 8 rows each (wave-uniform)

    float accK[8], accQ[8], accV[8], accS[8];
#pragma unroll
    for (int j = 0; j < 8; j++) { accK[j] = accQ[j] = accV[j] = accS[j] = 0.f; }

    for (int k = 0; k < 64; k++) {
        const float wk = sW[0][k * 64 + c];
        const float wq = sW[1][k * 64 + c];
        const float wv = sW[2][k * 64 + c];
        const float ws = sW[3][k * 64 + c];
#pragma unroll
        for (int j = 0; j < 8; j++) {
            const float x = sX[(rg * 8 + j) * 64 + k];  // wave-broadcast
            accK[j] = fmaf(x, wk, accK[j]);
            accQ[j] = fmaf(x, wq, accQ[j]);
            accV[j] = fmaf(x, wv, accV[j]);
            accS[j] = fmaf(x, ws, accS[j]);
        }
    }

    const float bkc = bk[c], bqc = bq[c], bvc = bv[c], bsc = bs[c];
#pragma unroll
    for (int j = 0; j < 8; j++) {
        const int r = row0 + rg * 8 + j;
        if (r < NN) {
            const size_t o = (size_t)r * DD + c;
            K[o]   = accK[j] + bkc;
            Q[o]   = accQ[j] + bqc;
            V[o]   = accV[j] + bvc;
            OUT[o] = accS[j] + bsc;
        }
    }
}

// ---------------------------------------------------------------------------
// Edge kernel: for each edge (src -> dst):
//   AGG[dst] += sigmoid(K[dst] + Q[src]) * V[src]
// 16 threads per edge, float4 per thread, 4 atomics per thread.
// ---------------------------------------------------------------------------
__global__ __launch_bounds__(256) void edge_kernel(
    const int* __restrict__ ei,
    const float* __restrict__ K, const float* __restrict__ Q,
    const float* __restrict__ V, float* __restrict__ AGG)
{
    const int t = blockIdx.x * 256 + threadIdx.x;
    const int e = t >> 4;
    if (e >= NE) return;
    const int j = (t & 15) * 4;

    const int src = ei[e];
    const int dst = ei[NE + e];

    const float4 q = *(const float4*)(Q + (size_t)src * DD + j);
    const float4 k = *(const float4*)(K + (size_t)dst * DD + j);
    const float4 v = *(const float4*)(V + (size_t)src * DD + j);

    const float gx = 1.f / (1.f + __expf(-(k.x + q.x)));
    const float gy = 1.f / (1.f + __expf(-(k.y + q.y)));
    const float gz = 1.f / (1.f + __expf(-(k.z + q.z)));
    const float gw = 1.f / (1.f + __expf(-(k.w + q.w)));

    float* out = AGG + (size_t)dst * DD + j;
    atomicAdd(out + 0, gx * v.x);
    atomicAdd(out + 1, gy * v.y);
    atomicAdd(out + 2, gz * v.z);
    atomicAdd(out + 3, gw * v.w);
}

// ---------------------------------------------------------------------------
// Column-wise sum / sumsq of relu(AGG) -> stats[0:64] = sum, stats[64:128] = sumsq
// ---------------------------------------------------------------------------
__global__ __launch_bounds__(256) void stats_kernel(
    const float* __restrict__ AGG, float* __restrict__ stats)
{
    const int c  = threadIdx.x & 63;
    const int rg = threadIdx.x >> 6;
    float s = 0.f, s2 = 0.f;
    for (int r = blockIdx.x * 4 + rg; r < NN; r += gridDim.x * 4) {
        float x = AGG[(size_t)r * DD + c];
        x = fmaxf(x, 0.f);
        s += x;
        s2 += x * x;
    }
    __shared__ float ls[256], ls2[256];
    ls[threadIdx.x] = s;
    ls2[threadIdx.x] = s2;
    __syncthreads();
    if (threadIdx.x < 64) {
        s  = ls[threadIdx.x]  + ls[threadIdx.x + 64]  + ls[threadIdx.x + 128]  + ls[threadIdx.x + 192];
        s2 = ls2[threadIdx.x] + ls2[threadIdx.x + 64] + ls2[threadIdx.x + 128] + ls2[threadIdx.x + 192];
        atomicAdd(&stats[c], s);
        atomicAdd(&stats[64 + c], s2);
    }
}

// ---------------------------------------------------------------------------
// BN apply (in-place ok): Hout = (relu(x) - mean) * rsqrt(var+eps) * gamma + beta
// ---------------------------------------------------------------------------
__global__ __launch_bounds__(256) void bn_apply_kernel(
    const float* __restrict__ AGG, const float* __restrict__ stats,
    const float* __restrict__ gamma, const float* __restrict__ beta,
    float* __restrict__ Hout)
{
    const int idx = blockIdx.x * 256 + threadIdx.x;
    if (idx >= NN * DD) return;
    const int c = idx & 63;
    const float invN = 1.0f / (float)NN;
    const float mean = stats[c] * invN;
    const float var  = stats[64 + c] * invN - mean * mean;
    const float inv  = rsqrtf(var + BN_EPS);
    float x = fmaxf(AGG[idx], 0.f);
    Hout[idx] = (x - mean) * inv * gamma[c] + beta[c];
}

// ---------------------------------------------------------------------------
// Pooled segment-sum. batch is sorted, so accumulate runs and flush atomics
// only on graph change. Block = 64 threads (one per column), each block owns
// a contiguous row range.
// ---------------------------------------------------------------------------
#define POOL_ROWS 196
__global__ __launch_bounds__(64) void pool_kernel(
    const float* __restrict__ H, const int* __restrict__ batch,
    float* __restrict__ psum, float* __restrict__ pcnt)
{
    const int c  = threadIdx.x;
    const int r0 = blockIdx.x * POOL_ROWS;
    if (r0 >= NN) return;
    const int r1 = min(r0 + POOL_ROWS, NN);

    int cur = batch[r0];
    float acc = 0.f, cnt = 0.f;
    for (int r = r0; r < r1; r++) {
        const int g = batch[r];  // wave-uniform
        if (g != cur) {
            atomicAdd(&psum[cur * DD + c], acc);
            if (c == 0) atomicAdd(&pcnt[cur], cnt);
            acc = 0.f; cnt = 0.f; cur = g;
        }
        acc += H[(size_t)r * DD + c];
        cnt += 1.f;
    }
    atomicAdd(&psum[cur * DD + c], acc);
    if (c == 0) atomicAdd(&pcnt[cur], cnt);
}

// ---------------------------------------------------------------------------
// Final: pooled mean -> logits -> softmax. One thread per graph.
// ---------------------------------------------------------------------------
__global__ __launch_bounds__(256) void final_kernel(
    const float* __restrict__ psum, const float* __restrict__ pcnt,
    const float* __restrict__ Wlin, const float* __restrict__ blin,
    float* __restrict__ out)
{
    const int g = blockIdx.x * blockDim.x + threadIdx.x;
    if (g >= NG) return;

    const float invc = 1.0f / fmaxf(pcnt[g], 1.0f);
    float p[DD];
#pragma unroll
    for (int d = 0; d < DD; d++) p[d] = psum[g * DD + d] * invc;

    float logits[NC];
    float m = -1e30f;
#pragma unroll
    for (int c = 0; c < NC; c++) {
        float acc = blin[c];
#pragma unroll
        for (int d = 0; d < DD; d++) acc = fmaf(p[d], Wlin[d * NC + c], acc);
        logits[c] = acc;
        m = fmaxf(m, acc);
    }
    float sum = 0.f;
#pragma unroll
    for (int c = 0; c < NC; c++) {
        logits[c] = __expf(logits[c] - m);
        sum += logits[c];
    }
    const float inv = 1.f / sum;
#pragma unroll
    for (int c = 0; c < NC; c++) out[g * NC + c] = logits[c] * inv;
}

// ---------------------------------------------------------------------------
extern "C" void kernel_launch(void* const* d_in, const int* in_sizes, int n_in,
                              void* d_out, int out_size, void* d_ws, size_t ws_size,
                              hipStream_t stream)
{
    const float* X     = (const float*)d_in[0];
    const int*   ei    = (const int*)d_in[1];
    const int*   batch = (const int*)d_in[2];
    const float* Wk    = (const float*)d_in[3];
    const float* Wq    = (const float*)d_in[4];
    const float* Wv    = (const float*)d_in[5];
    const float* Ws    = (const float*)d_in[6];
    const float* bk    = (const float*)d_in[7];
    const float* bq    = (const float*)d_in[8];
    const float* bv    = (const float*)d_in[9];
    const float* bconv = (const float*)d_in[10];
    const float* gamma = (const float*)d_in[11];
    const float* beta  = (const float*)d_in[12];
    const float* Wlin  = (const float*)d_in[13];
    const float* blin  = (const float*)d_in[14];
    float* out = (float*)d_out;

    float* ws = (float*)d_ws;
    const size_t M = (size_t)NN * DD;
    float* K     = ws;
    float* Q     = K + M;
    float* V     = Q + M;
    float* H0    = V + M;
    float* H1    = H0 + M;
    float* stats = H1 + M;              // 128 floats
    float* psum  = stats + 128;         // NG*64
    float* pcnt  = psum + (size_t)NG * DD;  // NG

    const float* hin = X;
    for (int l = 0; l < NL; l++) {
        float* hout = (l & 1) ? H1 : H0;
        gemm4_kernel<<<(NN + 31) / 32, 256, 0, stream>>>(
            hin, Wk + l * 4096, Wq + l * 4096, Wv + l * 4096, Ws + l * 4096,
            bk + l * 64, bq + l * 64, bv + l * 64, bconv + l * 64,
            K, Q, V, hout);
        edge_kernel<<<(NE * 16) / 256, 256, 0, stream>>>(ei, K, Q, V, hout);
        hipMemsetAsync(stats, 0, 128 * sizeof(float), stream);
        stats_kernel<<<512, 256, 0, stream>>>(hout, stats);
        bn_apply_kernel<<<(NN * DD) / 256 + 1, 256, 0, stream>>>(
            hout, stats, gamma + l * 64, beta + l * 64, hout);
        hin = hout;
    }

    hipMemsetAsync(psum, 0, (size_t)(NG * DD + NG) * sizeof(float), stream);
    pool_kernel<<<(NN + POOL_ROWS - 1) / POOL_ROWS, 64, 0, stream>>>(hin, batch, psum, pcnt);
    final_kernel<<<1, 256, 0, stream>>>(psum, pcnt, Wlin, blin, out);
}

// Round 2
// 1104.471 us; speedup vs baseline: 3.5601x; 3.5601x over previous
//
#include <hip/hip_runtime.h>

#define NN 50000
#define NE 800000
#define DD 64
#define NL 5
#define NG 256
#define NC 10
#define BN_EPS 1e-5f
#define NCHUNK ((NN + 255) / 256)   // 196

// ---------------------------------------------------------------------------
// Fused 4-matrix GEMM: K = Hin@Wk + bk, QV (interleaved) = Hin@{Wq,Wv} + b,
// OUT = Hin@Ws + bs (skip path; gather adds the aggregation in-place later).
// In-place safe (Hin == OUT): block stages its 32 rows to LDS before writing.
// ---------------------------------------------------------------------------
__global__ __launch_bounds__(256) void gemm4_kernel(
    const float* Hin,
    const float* __restrict__ Wk, const float* __restrict__ Wq,
    const float* __restrict__ Wv, const float* __restrict__ Ws,
    const float* __restrict__ bk, const float* __restrict__ bq,
    const float* __restrict__ bv, const float* __restrict__ bs,
    float* __restrict__ K, float* __restrict__ QV, float* OUT)
{
    __shared__ float sW[4][64 * 64];
    __shared__ float sX[32 * 64];
    const int tid = threadIdx.x;

    for (int i = tid; i < 4096; i += 256) {
        sW[0][i] = Wk[i];
        sW[1][i] = Wq[i];
        sW[2][i] = Wv[i];
        sW[3][i] = Ws[i];
    }

    const int row0 = blockIdx.x * 32;
    float4* sX4 = (float4*)sX;
    const float4* Hin4 = (const float4*)(Hin + (size_t)row0 * DD);
    for (int i = tid; i < 32 * 16; i += 256) {
        int r = row0 + (i >> 4);
        sX4[i] = (r < NN) ? Hin4[i] : make_float4(0.f, 0.f, 0.f, 0.f);
    }
    __syncthreads();

    const int c  = tid & 63;
    const int rg = tid >> 6;

    float accK[8], accQ[8], accV[8], accS[8];
#pragma unroll
    for (int j = 0; j < 8; j++) { accK[j] = accQ[j] = accV[j] = accS[j] = 0.f; }

    for (int k = 0; k < 64; k++) {
        const float wk = sW[0][k * 64 + c];
        const float wq = sW[1][k * 64 + c];
        const float wv = sW[2][k * 64 + c];
        const float ws = sW[3][k * 64 + c];
#pragma unroll
        for (int j = 0; j < 8; j++) {
            const float x = sX[(rg * 8 + j) * 64 + k];
            accK[j] = fmaf(x, wk, accK[j]);
            accQ[j] = fmaf(x, wq, accQ[j]);
            accV[j] = fmaf(x, wv, accV[j]);
            accS[j] = fmaf(x, ws, accS[j]);
        }
    }

    const float bkc = bk[c], bqc = bq[c], bvc = bv[c], bsc = bs[c];
#pragma unroll
    for (int j = 0; j < 8; j++) {
        const int r = row0 + rg * 8 + j;
        if (r < NN) {
            K[(size_t)r * DD + c]            = accK[j] + bkc;
            QV[(size_t)r * 2 * DD + c]       = accQ[j] + bqc;
            QV[(size_t)r * 2 * DD + DD + c]  = accV[j] + bvc;
            OUT[(size_t)r * DD + c]          = accS[j] + bsc;
        }
    }
}

// ---------------------------------------------------------------------------
// CSR build: histogram of dst, two-level exclusive scan, scatter fill.
// ---------------------------------------------------------------------------
__global__ __launch_bounds__(256) void deg_kernel(
    const int* __restrict__ ei, int* __restrict__ deg)
{
    const int e = blockIdx.x * 256 + threadIdx.x;
    if (e < NE) atomicAdd(&deg[ei[NE + e]], 1);
}

__global__ __launch_bounds__(256) void scan_partial_kernel(
    const int* __restrict__ deg, int* __restrict__ psums)
{
    __shared__ int ls[256];
    const int i = blockIdx.x * 256 + threadIdx.x;
    ls[threadIdx.x] = (i < NN) ? deg[i] : 0;
    __syncthreads();
    for (int off = 128; off > 0; off >>= 1) {
        if (threadIdx.x < off) ls[threadIdx.x] += ls[threadIdx.x + off];
        __syncthreads();
    }
    if (threadIdx.x == 0) psums[blockIdx.x] = ls[0];
}

__global__ void scan_offsets_kernel(int* __restrict__ psums, int* __restrict__ rowst)
{
    if (threadIdx.x == 0) {
        int running = 0;
        for (int i = 0; i < NCHUNK; i++) {
            int t = psums[i];
            psums[i] = running;
            running += t;
        }
        rowst[NN] = running;  // == NE
    }
}

__global__ __launch_bounds__(256) void scan_final_kernel(
    const int* __restrict__ deg, const int* __restrict__ psums,
    int* __restrict__ rowst, int* __restrict__ cursor)
{
    __shared__ int ls[256];
    const int i = blockIdx.x * 256 + threadIdx.x;
    const int x = (i < NN) ? deg[i] : 0;
    ls[threadIdx.x] = x;
    __syncthreads();
    // Hillis-Steele inclusive scan
    for (int off = 1; off < 256; off <<= 1) {
        int v = (threadIdx.x >= off) ? ls[threadIdx.x - off] : 0;
        __syncthreads();
        ls[threadIdx.x] += v;
        __syncthreads();
    }
    if (i < NN) {
        const int excl = psums[blockIdx.x] + ls[threadIdx.x] - x;
        rowst[i]  = excl;
        cursor[i] = excl;
    }
}

__global__ __launch_bounds__(256) void fill_kernel(
    const int* __restrict__ ei, int* __restrict__ cursor, int* __restrict__ csr)
{
    const int e = blockIdx.x * 256 + threadIdx.x;
    if (e < NE) {
        const int src = ei[e];
        const int dst = ei[NE + e];
        csr[atomicAdd(&cursor[dst], 1)] = src;
    }
}

// ---------------------------------------------------------------------------
// Gather: one 64-lane wave per dst node. acc += sigmoid(K[dst]+Q[src])*V[src]
// over in-edges. H updated in place: H = relu(H_skip + acc). Fused BN stats.
// ---------------------------------------------------------------------------
#define GATHER_BLOCKS 2048
__global__ __launch_bounds__(256) void gather_kernel(
    const int* __restrict__ rowst, const int* __restrict__ csr,
    const float* __restrict__ K, const float* __restrict__ QV,
    float* H, float* __restrict__ stats)
{
    const int c  = threadIdx.x & 63;
    const int rg = threadIdx.x >> 6;
    float s = 0.f, s2 = 0.f;

    for (int n = blockIdx.x * 4 + rg; n < NN; n += GATHER_BLOCKS * 4) {
        const float k = K[(size_t)n * DD + c];
        const int e0 = rowst[n], e1 = rowst[n + 1];
        float acc = 0.f;
        for (int i = e0; i < e1; i++) {
            const int sidx = csr[i];
            const float q = QV[(size_t)sidx * 2 * DD + c];
            const float v = QV[(size_t)sidx * 2 * DD + DD + c];
            acc = fmaf(1.f / (1.f + __expf(-(k + q))), v, acc);
        }
        float o = H[(size_t)n * DD + c] + acc;
        o = fmaxf(o, 0.f);
        H[(size_t)n * DD + c] = o;
        s += o;
        s2 += o * o;
    }

    __shared__ float ls[256], ls2[256];
    ls[threadIdx.x]  = s;
    ls2[threadIdx.x] = s2;
    __syncthreads();
    if (threadIdx.x < 64) {
        s  = ls[threadIdx.x]  + ls[threadIdx.x + 64]  + ls[threadIdx.x + 128]  + ls[threadIdx.x + 192];
        s2 = ls2[threadIdx.x] + ls2[threadIdx.x + 64] + ls2[threadIdx.x + 128] + ls2[threadIdx.x + 192];
        atomicAdd(&stats[c], s);
        atomicAdd(&stats[64 + c], s2);
    }
}

// ---------------------------------------------------------------------------
// BN apply in place (input already relu'd by gather).
// ---------------------------------------------------------------------------
__global__ __launch_bounds__(256) void bn_apply_kernel(
    float* H, const float* __restrict__ stats,
    const float* __restrict__ gamma, const float* __restrict__ beta)
{
    const int idx = blockIdx.x * 256 + threadIdx.x;
    if (idx >= NN * DD) return;
    const int c = idx & 63;
    const float invN = 1.0f / (float)NN;
    const float mean = stats[c] * invN;
    const float var  = stats[64 + c] * invN - mean * mean;
    const float inv  = rsqrtf(var + BN_EPS);
    H[idx] = (H[idx] - mean) * inv * gamma[c] + beta[c];
}

// ---------------------------------------------------------------------------
// Pooled segment-sum (batch sorted -> run-length accumulate, flush on change).
// ---------------------------------------------------------------------------
#define POOL_ROWS 196
__global__ __launch_bounds__(64) void pool_kernel(
    const float* __restrict__ H, const int* __restrict__ batch,
    float* __restrict__ psum, float* __restrict__ pcnt)
{
    const int c  = threadIdx.x;
    const int r0 = blockIdx.x * POOL_ROWS;
    if (r0 >= NN) return;
    const int r1 = min(r0 + POOL_ROWS, NN);

    int cur = batch[r0];
    float acc = 0.f, cnt = 0.f;
    for (int r = r0; r < r1; r++) {
        const int g = batch[r];
        if (g != cur) {
            atomicAdd(&psum[cur * DD + c], acc);
            if (c == 0) atomicAdd(&pcnt[cur], cnt);
            acc = 0.f; cnt = 0.f; cur = g;
        }
        acc += H[(size_t)r * DD + c];
        cnt += 1.f;
    }
    atomicAdd(&psum[cur * DD + c], acc);
    if (c == 0) atomicAdd(&pcnt[cur], cnt);
}

__global__ __launch_bounds__(256) void final_kernel(
    const float* __restrict__ psum, const float* __restrict__ pcnt,
    const float* __restrict__ Wlin, const float* __restrict__ blin,
    float* __restrict__ out)
{
    const int g = blockIdx.x * blockDim.x + threadIdx.x;
    if (g >= NG) return;

    const float invc = 1.0f / fmaxf(pcnt[g], 1.0f);
    float p[DD];
#pragma unroll
    for (int d = 0; d < DD; d++) p[d] = psum[g * DD + d] * invc;

    float logits[NC];
    float m = -1e30f;
#pragma unroll
    for (int c = 0; c < NC; c++) {
        float acc = blin[c];
#pragma unroll
        for (int d = 0; d < DD; d++) acc = fmaf(p[d], Wlin[d * NC + c], acc);
        logits[c] = acc;
        m = fmaxf(m, acc);
    }
    float sum = 0.f;
#pragma unroll
    for (int c = 0; c < NC; c++) {
        logits[c] = __expf(logits[c] - m);
        sum += logits[c];
    }
    const float inv = 1.f / sum;
#pragma unroll
    for (int c = 0; c < NC; c++) out[g * NC + c] = logits[c] * inv;
}

// ---------------------------------------------------------------------------
extern "C" void kernel_launch(void* const* d_in, const int* in_sizes, int n_in,
                              void* d_out, int out_size, void* d_ws, size_t ws_size,
                              hipStream_t stream)
{
    const float* X     = (const float*)d_in[0];
    const int*   ei    = (const int*)d_in[1];
    const int*   batch = (const int*)d_in[2];
    const float* Wk    = (const float*)d_in[3];
    const float* Wq    = (const float*)d_in[4];
    const float* Wv    = (const float*)d_in[5];
    const float* Ws    = (const float*)d_in[6];
    const float* bk    = (const float*)d_in[7];
    const float* bq    = (const float*)d_in[8];
    const float* bv    = (const float*)d_in[9];
    const float* bconv = (const float*)d_in[10];
    const float* gamma = (const float*)d_in[11];
    const float* beta  = (const float*)d_in[12];
    const float* Wlin  = (const float*)d_in[13];
    const float* blin  = (const float*)d_in[14];
    float* out = (float*)d_out;

    float* ws = (float*)d_ws;
    const size_t M = (size_t)NN * DD;
    float* K     = ws;                       // M
    float* QV    = K + M;                    // 2M (Q,V interleaved per row)
    float* H     = QV + 2 * M;               // M
    float* stats = H + M;                    // 128
    float* psum  = stats + 128;              // NG*DD
    float* pcnt  = psum + (size_t)NG * DD;   // NG
    int* deg     = (int*)(pcnt + NG);        // NN
    int* rowst   = deg + NN;                 // NN+1
    int* cursor  = rowst + NN + 1;           // NN
    int* psums   = cursor + NN;              // NCHUNK (<=256)
    int* csr     = psums + 256;              // NE

    // ---- CSR build (per call; inputs restored before every launch) ----
    hipMemsetAsync(deg, 0, NN * sizeof(int), stream);
    deg_kernel<<<(NE + 255) / 256, 256, 0, stream>>>(ei, deg);
    scan_partial_kernel<<<NCHUNK, 256, 0, stream>>>(deg, psums);
    scan_offsets_kernel<<<1, 64, 0, stream>>>(psums, rowst);
    scan_final_kernel<<<NCHUNK, 256, 0, stream>>>(deg, psums, rowst, cursor);
    fill_kernel<<<(NE + 255) / 256, 256, 0, stream>>>(ei, cursor, csr);

    // ---- layers ----
    const float* hin = X;
    for (int l = 0; l < NL; l++) {
        gemm4_kernel<<<(NN + 31) / 32, 256, 0, stream>>>(
            hin, Wk + l * 4096, Wq + l * 4096, Wv + l * 4096, Ws + l * 4096,
            bk + l * 64, bq + l * 64, bv + l * 64, bconv + l * 64,
            K, QV, H);
        hipMemsetAsync(stats, 0, 128 * sizeof(float), stream);
        gather_kernel<<<GATHER_BLOCKS, 256, 0, stream>>>(rowst, csr, K, QV, H, stats);
        bn_apply_kernel<<<(NN * DD + 255) / 256, 256, 0, stream>>>(
            H, stats, gamma + l * 64, beta + l * 64);
        hin = H;  // layers 1+ run gemm4 in place (block stages rows to LDS first)
    }

    hipMemsetAsync(psum, 0, (size_t)(NG * DD + NG) * sizeof(float), stream);
    pool_kernel<<<(NN + POOL_ROWS - 1) / POOL_ROWS, 64, 0, stream>>>(H, batch, psum, pcnt);
    final_kernel<<<1, 256, 0, stream>>>(psum, pcnt, Wlin, blin, out);
}

// Round 3
// 928.064 us; speedup vs baseline: 4.2368x; 1.1901x over previous
//
#include <hip/hip_runtime.h>

#define NN 50000
#define NE 800000
#define DD 64
#define NL 5
#define NG 256
#define NC 10
#define BN_EPS 1e-5f
#define NCHUNK ((NN + 255) / 256)   // 196

// Pack two floats as bf16 (RNE) into one uint: low16 = q, high16 = v.
__device__ inline unsigned int pack_bf16x2(float q, float v) {
    unsigned int uq = __float_as_uint(q);
    unsigned int uv = __float_as_uint(v);
    uq += 0x7FFFu + ((uq >> 16) & 1u);
    uv += 0x7FFFu + ((uv >> 16) & 1u);
    return (uv & 0xFFFF0000u) | (uq >> 16);
}

// ---------------------------------------------------------------------------
// Fused 4-matrix GEMM with folded BN of the PREVIOUS layer:
//   x' = x * a_c + b_c (BN affine, applied to the staged LDS tile)
//   K = x'@Wk + bk ; QV(packed bf16) = x'@{Wq,Wv} + b ; OUT = x'@Ws + bs
// In-place safe (Hin == OUT): block stages its 32 rows to LDS before writing.
// ---------------------------------------------------------------------------
__global__ __launch_bounds__(256) void gemm4_kernel(
    const float* Hin,
    const float* __restrict__ Wk, const float* __restrict__ Wq,
    const float* __restrict__ Wv, const float* __restrict__ Ws,
    const float* __restrict__ bk, const float* __restrict__ bq,
    const float* __restrict__ bv, const float* __restrict__ bs,
    const float* __restrict__ prevStats,   // 128 floats (sum, sumsq) or null
    const float* __restrict__ prevGamma, const float* __restrict__ prevBeta,
    float* __restrict__ K, unsigned int* __restrict__ QVp, float* OUT)
{
    __shared__ float sW[4][64 * 64];
    __shared__ float sX[32 * 64];
    __shared__ float sA[64], sB[64];
    const int tid = threadIdx.x;

    if (tid < 64) {
        float a = 1.f, b = 0.f;
        if (prevStats) {
            const float invN = 1.0f / (float)NN;
            const float mean = prevStats[tid] * invN;
            const float var  = prevStats[64 + tid] * invN - mean * mean;
            const float inv  = rsqrtf(var + BN_EPS);
            a = inv * prevGamma[tid];
            b = prevBeta[tid] - mean * a;
        }
        sA[tid] = a;
        sB[tid] = b;
    }

    for (int i = tid; i < 4096; i += 256) {
        sW[0][i] = Wk[i];
        sW[1][i] = Wq[i];
        sW[2][i] = Wv[i];
        sW[3][i] = Ws[i];
    }

    const int row0 = blockIdx.x * 32;
    float4* sX4 = (float4*)sX;
    const float4* Hin4 = (const float4*)(Hin + (size_t)row0 * DD);
    for (int i = tid; i < 32 * 16; i += 256) {
        int r = row0 + (i >> 4);
        sX4[i] = (r < NN) ? Hin4[i] : make_float4(0.f, 0.f, 0.f, 0.f);
    }
    __syncthreads();

    // BN affine on the staged tile
    if (prevStats) {
        for (int i = tid; i < 32 * 64; i += 256)
            sX[i] = fmaf(sX[i], sA[i & 63], sB[i & 63]);
    }
    __syncthreads();

    const int c  = tid & 63;
    const int rg = tid >> 6;

    float accK[8], accQ[8], accV[8], accS[8];
#pragma unroll
    for (int j = 0; j < 8; j++) { accK[j] = accQ[j] = accV[j] = accS[j] = 0.f; }

    for (int k = 0; k < 64; k++) {
        const float wk = sW[0][k * 64 + c];
        const float wq = sW[1][k * 64 + c];
        const float wv = sW[2][k * 64 + c];
        const float ws = sW[3][k * 64 + c];
#pragma unroll
        for (int j = 0; j < 8; j++) {
            const float x = sX[(rg * 8 + j) * 64 + k];
            accK[j] = fmaf(x, wk, accK[j]);
            accQ[j] = fmaf(x, wq, accQ[j]);
            accV[j] = fmaf(x, wv, accV[j]);
            accS[j] = fmaf(x, ws, accS[j]);
        }
    }

    const float bkc = bk[c], bqc = bq[c], bvc = bv[c], bsc = bs[c];
#pragma unroll
    for (int j = 0; j < 8; j++) {
        const int r = row0 + rg * 8 + j;
        if (r < NN) {
            K[(size_t)r * DD + c]   = accK[j] + bkc;
            QVp[(size_t)r * DD + c] = pack_bf16x2(accQ[j] + bqc, accV[j] + bvc);
            OUT[(size_t)r * DD + c] = accS[j] + bsc;
        }
    }
}

// ---------------------------------------------------------------------------
// CSR build: histogram of dst, two-level exclusive scan, scatter fill.
// ---------------------------------------------------------------------------
__global__ __launch_bounds__(256) void deg_kernel(
    const int* __restrict__ ei, int* __restrict__ deg)
{
    const int e = blockIdx.x * 256 + threadIdx.x;
    if (e < NE) atomicAdd(&deg[ei[NE + e]], 1);
}

__global__ __launch_bounds__(256) void scan_partial_kernel(
    const int* __restrict__ deg, int* __restrict__ psums)
{
    __shared__ int ls[256];
    const int i = blockIdx.x * 256 + threadIdx.x;
    ls[threadIdx.x] = (i < NN) ? deg[i] : 0;
    __syncthreads();
    for (int off = 128; off > 0; off >>= 1) {
        if (threadIdx.x < off) ls[threadIdx.x] += ls[threadIdx.x + off];
        __syncthreads();
    }
    if (threadIdx.x == 0) psums[blockIdx.x] = ls[0];
}

__global__ void scan_offsets_kernel(int* __restrict__ psums, int* __restrict__ rowst)
{
    if (threadIdx.x == 0) {
        int running = 0;
        for (int i = 0; i < NCHUNK; i++) {
            int t = psums[i];
            psums[i] = running;
            running += t;
        }
        rowst[NN] = running;  // == NE
    }
}

__global__ __launch_bounds__(256) void scan_final_kernel(
    const int* __restrict__ deg, const int* __restrict__ psums,
    int* __restrict__ rowst, int* __restrict__ cursor)
{
    __shared__ int ls[256];
    const int i = blockIdx.x * 256 + threadIdx.x;
    const int x = (i < NN) ? deg[i] : 0;
    ls[threadIdx.x] = x;
    __syncthreads();
    for (int off = 1; off < 256; off <<= 1) {
        int v = (threadIdx.x >= off) ? ls[threadIdx.x - off] : 0;
        __syncthreads();
        ls[threadIdx.x] += v;
        __syncthreads();
    }
    if (i < NN) {
        const int excl = psums[blockIdx.x] + ls[threadIdx.x] - x;
        rowst[i]  = excl;
        cursor[i] = excl;
    }
}

__global__ __launch_bounds__(256) void fill_kernel(
    const int* __restrict__ ei, int* __restrict__ cursor, int* __restrict__ csr)
{
    const int e = blockIdx.x * 256 + threadIdx.x;
    if (e < NE) {
        const int src = ei[e];
        const int dst = ei[NE + e];
        csr[atomicAdd(&cursor[dst], 1)] = src;
    }
}

// ---------------------------------------------------------------------------
// Gather: one 64-lane wave per dst node. Per edge: one packed uint read
// (bf16 q|v), gate, fma. H = relu(H_skip + acc) in place + fused BN stats.
// ---------------------------------------------------------------------------
#define GATHER_BLOCKS 2048
__global__ __launch_bounds__(256) void gather_kernel(
    const int* __restrict__ rowst, const int* __restrict__ csr,
    const float* __restrict__ K, const unsigned int* __restrict__ QVp,
    float* H, float* __restrict__ stats)
{
    const int c  = threadIdx.x & 63;
    const int rg = threadIdx.x >> 6;
    float s = 0.f, s2 = 0.f;

    for (int n = blockIdx.x * 4 + rg; n < NN; n += GATHER_BLOCKS * 4) {
        const float k = K[(size_t)n * DD + c];
        const int e0 = rowst[n], e1 = rowst[n + 1];
        float acc = 0.f;
        int i = e0;
        for (; i + 2 <= e1; i += 2) {
            const int s0 = csr[i], s1 = csr[i + 1];
            const unsigned int p0 = QVp[(size_t)s0 * DD + c];
            const unsigned int p1 = QVp[(size_t)s1 * DD + c];
            const float q0 = __uint_as_float(p0 << 16);
            const float v0 = __uint_as_float(p0 & 0xFFFF0000u);
            const float q1 = __uint_as_float(p1 << 16);
            const float v1 = __uint_as_float(p1 & 0xFFFF0000u);
            acc = fmaf(1.f / (1.f + __expf(-(k + q0))), v0, acc);
            acc = fmaf(1.f / (1.f + __expf(-(k + q1))), v1, acc);
        }
        if (i < e1) {
            const unsigned int p0 = QVp[(size_t)csr[i] * DD + c];
            const float q0 = __uint_as_float(p0 << 16);
            const float v0 = __uint_as_float(p0 & 0xFFFF0000u);
            acc = fmaf(1.f / (1.f + __expf(-(k + q0))), v0, acc);
        }
        float o = H[(size_t)n * DD + c] + acc;
        o = fmaxf(o, 0.f);
        H[(size_t)n * DD + c] = o;
        s += o;
        s2 += o * o;
    }

    __shared__ float ls[256], ls2[256];
    ls[threadIdx.x]  = s;
    ls2[threadIdx.x] = s2;
    __syncthreads();
    if (threadIdx.x < 64) {
        s  = ls[threadIdx.x]  + ls[threadIdx.x + 64]  + ls[threadIdx.x + 128]  + ls[threadIdx.x + 192];
        s2 = ls2[threadIdx.x] + ls2[threadIdx.x + 64] + ls2[threadIdx.x + 128] + ls2[threadIdx.x + 192];
        atomicAdd(&stats[c], s);
        atomicAdd(&stats[64 + c], s2);
    }
}

// ---------------------------------------------------------------------------
// Pooled segment-sum (batch sorted -> run-length accumulate, flush on change).
// ---------------------------------------------------------------------------
#define POOL_ROWS 196
__global__ __launch_bounds__(64) void pool_kernel(
    const float* __restrict__ H, const int* __restrict__ batch,
    float* __restrict__ psum, float* __restrict__ pcnt)
{
    const int c  = threadIdx.x;
    const int r0 = blockIdx.x * POOL_ROWS;
    if (r0 >= NN) return;
    const int r1 = min(r0 + POOL_ROWS, NN);

    int cur = batch[r0];
    float acc = 0.f, cnt = 0.f;
    for (int r = r0; r < r1; r++) {
        const int g = batch[r];
        if (g != cur) {
            atomicAdd(&psum[cur * DD + c], acc);
            if (c == 0) atomicAdd(&pcnt[cur], cnt);
            acc = 0.f; cnt = 0.f; cur = g;
        }
        acc += H[(size_t)r * DD + c];
        cnt += 1.f;
    }
    atomicAdd(&psum[cur * DD + c], acc);
    if (c == 0) atomicAdd(&pcnt[cur], cnt);
}

// ---------------------------------------------------------------------------
// Final: pooled mean -> (folded last-layer BN affine) -> logits -> softmax.
// ---------------------------------------------------------------------------
__global__ __launch_bounds__(256) void final_kernel(
    const float* __restrict__ psum, const float* __restrict__ pcnt,
    const float* __restrict__ stats,
    const float* __restrict__ gamma, const float* __restrict__ beta,
    const float* __restrict__ Wlin, const float* __restrict__ blin,
    float* __restrict__ out)
{
    const int g = blockIdx.x * blockDim.x + threadIdx.x;
    if (g >= NG) return;

    const float invc = 1.0f / fmaxf(pcnt[g], 1.0f);
    const float invN = 1.0f / (float)NN;
    float p[DD];
#pragma unroll
    for (int d = 0; d < DD; d++) {
        const float mean = stats[d] * invN;
        const float var  = stats[64 + d] * invN - mean * mean;
        const float inv  = rsqrtf(var + BN_EPS);
        const float a = inv * gamma[d];
        const float b = beta[d] - mean * a;
        p[d] = fmaf(psum[g * DD + d] * invc, a, b);
    }

    float logits[NC];
    float m = -1e30f;
#pragma unroll
    for (int c = 0; c < NC; c++) {
        float acc = blin[c];
#pragma unroll
        for (int d = 0; d < DD; d++) acc = fmaf(p[d], Wlin[d * NC + c], acc);
        logits[c] = acc;
        m = fmaxf(m, acc);
    }
    float sum = 0.f;
#pragma unroll
    for (int c = 0; c < NC; c++) {
        logits[c] = __expf(logits[c] - m);
        sum += logits[c];
    }
    const float inv = 1.f / sum;
#pragma unroll
    for (int c = 0; c < NC; c++) out[g * NC + c] = logits[c] * inv;
}

// ---------------------------------------------------------------------------
extern "C" void kernel_launch(void* const* d_in, const int* in_sizes, int n_in,
                              void* d_out, int out_size, void* d_ws, size_t ws_size,
                              hipStream_t stream)
{
    const float* X     = (const float*)d_in[0];
    const int*   ei    = (const int*)d_in[1];
    const int*   batch = (const int*)d_in[2];
    const float* Wk    = (const float*)d_in[3];
    const float* Wq    = (const float*)d_in[4];
    const float* Wv    = (const float*)d_in[5];
    const float* Ws    = (const float*)d_in[6];
    const float* bk    = (const float*)d_in[7];
    const float* bq    = (const float*)d_in[8];
    const float* bv    = (const float*)d_in[9];
    const float* bconv = (const float*)d_in[10];
    const float* gamma = (const float*)d_in[11];
    const float* beta  = (const float*)d_in[12];
    const float* Wlin  = (const float*)d_in[13];
    const float* blin  = (const float*)d_in[14];
    float* out = (float*)d_out;

    float* ws = (float*)d_ws;
    const size_t M = (size_t)NN * DD;
    float*        K     = ws;                       // M
    unsigned int* QVp   = (unsigned int*)(K + M);   // M (packed bf16 q|v)
    float*        H     = (float*)(QVp + M);        // M
    // --- contiguous zero-init region ---
    int*   deg   = (int*)(H + M);                   // NN
    float* psum  = (float*)(deg + NN);              // NG*DD
    float* pcnt  = psum + (size_t)NG * DD;          // NG
    float* stats = pcnt + NG;                       // NL*128
    // --- end zero region ---
    int* rowst  = (int*)(stats + NL * 128);         // NN+1
    int* cursor = rowst + NN + 1;                   // NN
    int* psums  = cursor + NN;                      // 256
    int* csr    = psums + 256;                      // NE

    const size_t zero_bytes = (size_t)(NN + NG * DD + NG + NL * 128) * sizeof(float);
    hipMemsetAsync(deg, 0, zero_bytes, stream);

    // ---- CSR build ----
    deg_kernel<<<(NE + 255) / 256, 256, 0, stream>>>(ei, deg);
    scan_partial_kernel<<<NCHUNK, 256, 0, stream>>>(deg, psums);
    scan_offsets_kernel<<<1, 64, 0, stream>>>(psums, rowst);
    scan_final_kernel<<<NCHUNK, 256, 0, stream>>>(deg, psums, rowst, cursor);
    fill_kernel<<<(NE + 255) / 256, 256, 0, stream>>>(ei, cursor, csr);

    // ---- layers (BN folded into next GEMM / final) ----
    const float* hin = X;
    for (int l = 0; l < NL; l++) {
        const float* pS = (l == 0) ? nullptr : stats + (l - 1) * 128;
        const float* pG = (l == 0) ? nullptr : gamma + (l - 1) * 64;
        const float* pB = (l == 0) ? nullptr : beta  + (l - 1) * 64;
        gemm4_kernel<<<(NN + 31) / 32, 256, 0, stream>>>(
            hin, Wk + l * 4096, Wq + l * 4096, Wv + l * 4096, Ws + l * 4096,
            bk + l * 64, bq + l * 64, bv + l * 64, bconv + l * 64,
            pS, pG, pB, K, QVp, H);
        gather_kernel<<<GATHER_BLOCKS, 256, 0, stream>>>(
            rowst, csr, K, QVp, H, stats + l * 128);
        hin = H;
    }

    pool_kernel<<<(NN + POOL_ROWS - 1) / POOL_ROWS, 64, 0, stream>>>(H, batch, psum, pcnt);
    final_kernel<<<1, 256, 0, stream>>>(
        psum, pcnt, stats + 4 * 128, gamma + 4 * 64, beta + 4 * 64, Wlin, blin, out);
}